// Round 7
// baseline (132.121 us; speedup 1.0000x reference)
//
#include <hip/hip_runtime.h>

#define DEVI __device__ __forceinline__

typedef int i32x4 __attribute__((ext_vector_type(4)));

static constexpr int Bdim = 2048;
static constexpr int Kdim = 4096;
static constexpr int Ndim = 8192;
static constexpr int BK   = 128;         // int8 k-elements per tile (128 B/row)
static constexpr int NT   = Kdim / BK;   // 32 K-tiles

typedef __attribute__((address_space(1))) const unsigned int gas_t;
typedef __attribute__((address_space(3))) unsigned int las_t;
typedef __attribute__((address_space(3))) const char lds_cchar;

DEVI void gload_lds16(const void* g, void* l) {
    __builtin_amdgcn_global_load_lds((gas_t*)g, (las_t*)l, 16, 0, 0);
}

DEVI i32x4 dsread128(lds_cchar* p) {
    i32x4 r;
    asm volatile("ds_read_b128 %0, %1" : "=v"(r) : "v"(p));
    return r;
}

DEVI i32x4 gload128(const char* p) {
    i32x4 r;
    asm volatile("global_load_dwordx4 %0, %1, off" : "=v"(r) : "v"(p));
    return r;
}

DEVI int pack4(i32x4 v) {
    return (v[0] & 255) | ((v[1] & 255) << 8) | ((v[2] & 255) << 16) | (v[3] << 24);
}

// ---------------- pack: int32 -> int8 ----------------
__global__ void pack_i32_to_i8(const int* __restrict__ in, char* __restrict__ out, int n16) {
    int i = blockIdx.x * blockDim.x + threadIdx.x;
    if (i >= n16) return;
    const i32x4* src = (const i32x4*)in + (size_t)i * 4;
    i32x4 r;
    r[0] = pack4(src[0]);
    r[1] = pack4(src[1]);
    r[2] = pack4(src[2]);
    r[3] = pack4(src[3]);
    ((i32x4*)out)[i] = r;
}

// ---------------- 256x256 i8 GEMM: A via LDS, B direct from global ----------------
#define CFENCE asm volatile("" ::: "memory")
DEVI void bar() { CFENCE; __builtin_amdgcn_s_barrier(); CFENCE; }
#define WAITVM(N) asm volatile("s_waitcnt vmcnt(" #N ")" ::: "memory")
#define WAITLG0 asm volatile("s_waitcnt lgkmcnt(0)" ::: "memory")
#define SCHB __builtin_amdgcn_sched_barrier(0)
#define PRIO1 __builtin_amdgcn_s_setprio(1)
#define PRIO0 __builtin_amdgcn_s_setprio(0)

#define QX(MB, BREG)                                                             \
    do {                                                                         \
        _Pragma("unroll") for (int mm = 0; mm < 4; ++mm)                         \
        _Pragma("unroll") for (int n = 0; n < 4; ++n)                            \
            acc[(MB) + mm][n] = __builtin_amdgcn_mfma_i32_16x16x64_i8(           \
                a[mm], (BREG)[n], acc[(MB) + mm][n], 0, 0, 0);                   \
    } while (0)

// Per K-tile: 4 phases. b1(t) loaded in P1 (used P3/P4); b0(t+1) loaded in P3
// (used next P1/P2). A(t+1).ks1 staged P1; A(t+2).ks0 staged P3 (r6-proven
// stagger: each stage lands >=1 barrier after its region's last reader drained).
// WAITVM(2) at P1/P3 heads proves the 4 oldest B-loads; A-DMAs stay in flight.
#define TILE(CUR, W1, IB1, IA1, W2, IB0, IA0)                                       \
    {                                                                               \
        rdA(CUR, 0, 0); W1; IB1; IA1; bar(); WAITLG0; SCHB;                         \
        PRIO1; QX(0, b0); PRIO0; bar();                                             \
        rdA(CUR, 0, 4); bar(); WAITLG0; SCHB;                                       \
        PRIO1; QX(4, b0); PRIO0; bar();                                             \
        rdA(CUR, 1, 0); W2; IB0; IA0; bar(); WAITLG0; SCHB;                         \
        PRIO1; QX(0, b1); PRIO0; bar();                                             \
        rdA(CUR, 1, 4); bar(); WAITLG0; SCHB;                                       \
        PRIO1; QX(4, b1); PRIO0; bar();                                             \
    }

__global__ __launch_bounds__(512, 2)
void gemm8(const char* __restrict__ A8, const char* __restrict__ B8,
           const int* __restrict__ bias,
           const int* __restrict__ qm_p, const int* __restrict__ ex_p,
           const int* __restrict__ zp_p, int* __restrict__ out) {
    // LDS: A only: [2 buf][2 ks][256 rows][64 B] = 64 KiB
    __shared__ __align__(16) char smem[65536];
    lds_cchar* sbase = (lds_cchar*)smem;

    const int tid  = threadIdx.x;
    const int wid  = tid >> 6;
    const int lane = tid & 63;
    const int l15  = lane & 15;
    const int lks  = lane >> 4;
    const int wr   = wid >> 2;   // 0..1
    const int wc   = wid & 3;    // 0..3

    // XCD swizzle: 256 blocks, each XCD gets one bm stripe
    const int bid = blockIdx.x;
    const int swz = (bid & 7) * 32 + (bid >> 3);
    const int bm  = swz >> 5;    // 0..7
    const int bn  = swz & 31;    // 0..31
    const int arow0 = bm * 256;
    const int brow0 = bn * 256;

    // T2 swizzle for A (r6-proven): phys chunk = chunk ^ ((row>>1)&3)
    const int sw16 = (lks ^ ((l15 >> 1) & 3)) * 16;
    const int a_rd0 = (wr * 128 + l15) * 64 + sw16;

    // A stage addressing (r6-proven): thread -> row tid>>2 (+128), chunk st_c
    const int st_c = (tid & 3) ^ ((tid >> 3) & 3);
    const char* agp = A8 + (size_t)(arow0 + (tid >> 2)) * Kdim + st_c * 16;

    auto stage = [&](int t, int ks) {
        const char* gp = agp + (size_t)t * BK + ks * 64;
        const int lb = (t & 1) * 32768 + ks * 16384 + tid * 16;
        gload_lds16(gp, &smem[lb]);
        gload_lds16(gp + (size_t)128 * Kdim, &smem[lb + 8192]);
    };

    // B fragment pointers: lane reads 16 contiguous bytes of row (brow0+wc*64+n*16+l15)
    const char* bb[4];
#pragma unroll
    for (int n = 0; n < 4; ++n)
        bb[n] = B8 + (size_t)(brow0 + wc * 64 + n * 16 + l15) * Kdim + lks * 16;

    i32x4 acc[8][4] = {};
    i32x4 a[4], b0[4], b1[4];

    auto rdAimpl = [&](int buf, int ks, int h) {
#pragma unroll
        for (int m = 0; m < 4; ++m)
            a[m] = dsread128(sbase + (buf * 32768 + ks * 16384 + a_rd0 + (h + m) * 1024));
    };
#define rdA(BUF, KS, H) rdAimpl(BUF, KS, H)

    auto loadB = [&](i32x4* dst, int t, int kk) {
#pragma unroll
        for (int n = 0; n < 4; ++n)
            dst[n] = gload128(bb[n] + (size_t)t * BK + kk * 64);
    };

    // prologue: A(0).ks0, A(0).ks1, A(1).ks0 staged; b0(0) loaded; full drain once
    stage(0, 0); stage(0, 1); stage(1, 0);
    loadB(b0, 0, 0);
    WAITVM(0);
    bar();

    for (int t = 0; t < NT - 2; ++t) {   // steady: t = 0..29
        const int cur = t & 1;
        TILE(cur,
             WAITVM(2), loadB(b1, t, 1), stage(t + 1, 1),
             WAITVM(2), loadB(b0, t + 1, 0), stage(t + 2, 0));
    }
    // t = NT-2: no A(NT) stage
    TILE((NT - 2) & 1,
         WAITVM(2), loadB(b1, NT - 2, 1), stage(NT - 1, 1),
         WAITVM(2), loadB(b0, NT - 1, 0), ((void)0));
    // t = NT-1: only b1 load; full-drain waits (few loads left in flight)
    TILE((NT - 1) & 1,
         WAITVM(0), loadB(b1, NT - 1, 1), ((void)0),
         WAITVM(0), ((void)0), ((void)0));

    // ---------------- epilogue: requantize ----------------
    const int qm = *qm_p;
    const int ex = *ex_p;
    const int zp = *zp_p;
    const int rm = (qm < 2147418112) ? ((qm + (1 << 15)) >> 16) : 32767;
    const int shifts = 15 - ex;
    const long long rnd = (shifts > 0) ? (1LL << (shifts - 1)) : 0;

    int bv[4];
#pragma unroll
    for (int n = 0; n < 4; ++n) bv[n] = bias[brow0 + wc * 64 + n * 16 + l15];

#pragma unroll
    for (int m = 0; m < 8; ++m) {
        const int row0 = arow0 + wr * 128 + m * 16 + lks * 4;
#pragma unroll
        for (int n = 0; n < 4; ++n) {
            const int col = brow0 + wc * 64 + n * 16 + l15;
#pragma unroll
            for (int j = 0; j < 4; ++j) {
                long long t = (long long)(acc[m][n][j] + bv[n]) * rm + rnd;
                t >>= shifts;
                t += zp;
                t = t < -128 ? -128 : (t > 127 ? 127 : t);
                out[(size_t)(row0 + j) * Ndim + col] = (int)t;
            }
        }
    }
}

extern "C" void kernel_launch(void* const* d_in, const int* in_sizes, int n_in,
                              void* d_out, int out_size, void* d_ws, size_t ws_size,
                              hipStream_t stream) {
    const int* x32  = (const int*)d_in[0];
    const int* w32  = (const int*)d_in[1];
    const int* bias = (const int*)d_in[2];
    const int* qm   = (const int*)d_in[3];
    const int* ex   = (const int*)d_in[4];
    const int* zp   = (const int*)d_in[5];
    int* out = (int*)d_out;

    char* xa = (char*)d_ws;
    char* wa = xa + (size_t)Bdim * Kdim;
    const int nx16 = Bdim * Kdim / 16;   // 524288
    const int nw16 = Ndim * Kdim / 16;   // 2097152
    pack_i32_to_i8<<<(nx16 + 255) / 256, 256, 0, stream>>>(x32, xa, nx16);
    pack_i32_to_i8<<<(nw16 + 255) / 256, 256, 0, stream>>>(w32, wa, nw16);

    const int grid = (Bdim / 256) * (Ndim / 256);   // 8 * 32 = 256
    gemm8<<<grid, 512, 0, stream>>>(xa, wa, bias, qm, ex, zp, out);
}

// Round 8
// 119.499 us; speedup vs baseline: 1.1056x; 1.1056x over previous
//
#include <hip/hip_runtime.h>

#define DEVI __device__ __forceinline__

typedef int i32x4  __attribute__((ext_vector_type(4)));
typedef int i32x16 __attribute__((ext_vector_type(16)));

static constexpr int Bdim = 2048;
static constexpr int Kdim = 4096;
static constexpr int Ndim = 8192;
static constexpr int BK   = 64;          // int8 k per step (64 B rows)
static constexpr int NT   = Kdim / BK;   // 64 steps

typedef __attribute__((address_space(1))) const unsigned int gas_t;
typedef __attribute__((address_space(3))) unsigned int las_t;

DEVI void gload_lds16(const void* g, void* l) {
    __builtin_amdgcn_global_load_lds((gas_t*)g, (las_t*)l, 16, 0, 0);
}

DEVI int pack4(i32x4 v) {
    return (v[0] & 255) | ((v[1] & 255) << 8) | ((v[2] & 255) << 16) | (v[3] << 24);
}

// ---------------- pack: int32 -> int8 ----------------
__global__ void pack_i32_to_i8(const int* __restrict__ in, char* __restrict__ out, int n16) {
    int i = blockIdx.x * blockDim.x + threadIdx.x;
    if (i >= n16) return;
    const i32x4* src = (const i32x4*)in + (size_t)i * 4;
    i32x4 r;
    r[0] = pack4(src[0]);
    r[1] = pack4(src[1]);
    r[2] = pack4(src[2]);
    r[3] = pack4(src[3]);
    ((i32x4*)out)[i] = r;
}

// ---------- 128x256 tile, BK=64, 8 waves (64x64 each), 32x32x32 MFMA ----------
// 2 blocks/CU co-resident (LDS 48 KiB, VGPR<=128): inter-block TLP hides the
// per-block barrier/drain windows (m114). Simple 2-phase loop by design.
__global__ __launch_bounds__(512, 4)
void gemm2b(const char* __restrict__ A8, const char* __restrict__ B8,
            const int* __restrict__ bias,
            const int* __restrict__ qm_p, const int* __restrict__ ex_p,
            const int* __restrict__ zp_p, int* __restrict__ out) {
    // LDS per buf: A 128x64 (8 KiB) then B 256x64 (16 KiB); 2 bufs -> 48 KiB
    __shared__ __align__(16) char smem[49152];

    const int tid  = threadIdx.x;
    const int wid  = tid >> 6;
    const int lane = tid & 63;
    const int l31  = lane & 31;
    const int hc   = lane >> 5;            // 0..1: k-halfchunk within 32-k slice
    const int wr   = wid >> 2;             // 0..1 : 64-row band
    const int wc   = wid & 3;              // 0..3 : 64-col band

    // XCD-bijective swizzle (512 % 8 == 0)
    const int bid = blockIdx.x;
    const int swz = (bid & 7) * 64 + (bid >> 3);
    const int bm  = swz >> 5;              // 0..15
    const int bn  = swz & 31;              // 0..31
    const int arow0 = bm * 128;
    const int brow0 = bn * 256;

    // ---- staging: 1 A-DMA + 2 B-DMA per thread per step ----
    // LDS row r, slot s=tid&3 holds logical chunk c = s ^ ((r>>1)&3)
    const int st_c = (tid & 3) ^ ((tid >> 3) & 3);
    const char* agp = A8 + (size_t)(arow0 + (tid >> 2)) * Kdim + st_c * 16;
    const char* bgp = B8 + (size_t)(brow0 + (tid >> 2)) * Kdim + st_c * 16;

    auto stage = [&](int t) {
        const int buf = (t & 1) * 24576;
        gload_lds16(agp + (size_t)t * BK, &smem[buf + tid * 16]);
        gload_lds16(bgp + (size_t)t * BK, &smem[buf + 8192 + tid * 16]);
        gload_lds16(bgp + (size_t)128 * Kdim + (size_t)t * BK,
                    &smem[buf + 8192 + 8192 + tid * 16]);
    };

    // ---- fragment addresses (loop-invariant except buf) ----
    // row-major [row][64B]; logical chunk c at slot c ^ ((row>>1)&3)
    int aoff[2][2], boff[2][2];          // [s][m] / [s][n]
#pragma unroll
    for (int m = 0; m < 2; ++m) {
        const int row = wr * 64 + m * 32 + l31;
        const int xr  = (row >> 1) & 3;
#pragma unroll
        for (int s = 0; s < 2; ++s)
            aoff[s][m] = row * 64 + (((s * 2 + hc) ^ xr)) * 16;
    }
#pragma unroll
    for (int n = 0; n < 2; ++n) {
        const int row = wc * 64 + n * 32 + l31;
        const int xr  = (row >> 1) & 3;
#pragma unroll
        for (int s = 0; s < 2; ++s)
            boff[s][n] = 8192 + row * 64 + (((s * 2 + hc) ^ xr)) * 16;
    }

    i32x16 acc[2][2] = {};

    auto compute = [&](int t) {
        const int buf = (t & 1) * 24576;
        i32x4 a[2][2], b[2][2];
#pragma unroll
        for (int s = 0; s < 2; ++s)
#pragma unroll
            for (int m = 0; m < 2; ++m)
                a[s][m] = *(const i32x4*)&smem[buf + aoff[s][m]];
#pragma unroll
        for (int s = 0; s < 2; ++s)
#pragma unroll
            for (int n = 0; n < 2; ++n)
                b[s][n] = *(const i32x4*)&smem[buf + boff[s][n]];
#pragma unroll
        for (int m = 0; m < 2; ++m)
#pragma unroll
            for (int n = 0; n < 2; ++n)
#pragma unroll
                for (int s = 0; s < 2; ++s)
                    acc[m][n] = __builtin_amdgcn_mfma_i32_32x32x32_i8(
                        a[s][m], b[s][n], acc[m][n], 0, 0, 0);
    };

    stage(0);
    __syncthreads();
    for (int t = 0; t < NT; ++t) {
        if (t + 1 < NT) stage(t + 1);
        compute(t);
        __syncthreads();
    }

    // ---------------- epilogue: requantize ----------------
    const int qm = *qm_p;
    const int ex = *ex_p;
    const int zp = *zp_p;
    const int rm = (qm < 2147418112) ? ((qm + (1 << 15)) >> 16) : 32767;
    const int shifts = 15 - ex;
    const long long rnd = (shifts > 0) ? (1LL << (shifts - 1)) : 0;

    int bv[2];
#pragma unroll
    for (int n = 0; n < 2; ++n) bv[n] = bias[brow0 + wc * 64 + n * 32 + l31];

#pragma unroll
    for (int m = 0; m < 2; ++m) {
        const int rbase = arow0 + wr * 64 + m * 32 + hc * 4;
#pragma unroll
        for (int n = 0; n < 2; ++n) {
            const int col = brow0 + wc * 64 + n * 32 + l31;
#pragma unroll
            for (int j = 0; j < 16; ++j) {
                const int row = rbase + (j & 3) + (j >> 2) * 8;
                long long t = (long long)(acc[m][n][j] + bv[n]) * rm + rnd;
                t >>= shifts;
                t += zp;
                t = t < -128 ? -128 : (t > 127 ? 127 : t);
                out[(size_t)row * Ndim + col] = (int)t;
            }
        }
    }
}

extern "C" void kernel_launch(void* const* d_in, const int* in_sizes, int n_in,
                              void* d_out, int out_size, void* d_ws, size_t ws_size,
                              hipStream_t stream) {
    const int* x32  = (const int*)d_in[0];
    const int* w32  = (const int*)d_in[1];
    const int* bias = (const int*)d_in[2];
    const int* qm   = (const int*)d_in[3];
    const int* ex   = (const int*)d_in[4];
    const int* zp   = (const int*)d_in[5];
    int* out = (int*)d_out;

    char* xa = (char*)d_ws;
    char* wa = xa + (size_t)Bdim * Kdim;
    const int nx16 = Bdim * Kdim / 16;   // 524288
    const int nw16 = Ndim * Kdim / 16;   // 2097152
    pack_i32_to_i8<<<(nx16 + 255) / 256, 256, 0, stream>>>(x32, xa, nx16);
    pack_i32_to_i8<<<(nw16 + 255) / 256, 256, 0, stream>>>(w32, wa, nw16);

    const int grid = (Bdim / 128) * (Ndim / 256);   // 16 * 32 = 512
    gemm2b<<<grid, 512, 0, stream>>>(xa, wa, bias, qm, ex, zp, out);
}

// Round 9
// 119.202 us; speedup vs baseline: 1.1084x; 1.0025x over previous
//
#include <hip/hip_runtime.h>

#define DEVI __device__ __forceinline__

typedef int i32x4  __attribute__((ext_vector_type(4)));
typedef int i32x16 __attribute__((ext_vector_type(16)));

static constexpr int Bdim = 2048;
static constexpr int Kdim = 4096;
static constexpr int Ndim = 8192;
static constexpr int BK   = 64;          // int8 k per step (64 B rows)
static constexpr int NT   = Kdim / BK;   // 64 steps

typedef __attribute__((address_space(1))) const unsigned int gas_t;
typedef __attribute__((address_space(3))) unsigned int las_t;
typedef __attribute__((address_space(3))) const char lds_cchar;

DEVI void gload_lds16(const void* g, void* l) {
    __builtin_amdgcn_global_load_lds((gas_t*)g, (las_t*)l, 16, 0, 0);
}

DEVI i32x4 dsread128(lds_cchar* p) {
    i32x4 r;
    asm volatile("ds_read_b128 %0, %1" : "=v"(r) : "v"(p));
    return r;
}

DEVI int pack4(i32x4 v) {
    return (v[0] & 255) | ((v[1] & 255) << 8) | ((v[2] & 255) << 16) | (v[3] << 24);
}

#define WAITLG0 asm volatile("s_waitcnt lgkmcnt(0)" ::: "memory")
#define SCHB __builtin_amdgcn_sched_barrier(0)
#define PRIO1 __builtin_amdgcn_s_setprio(1)
#define PRIO0 __builtin_amdgcn_s_setprio(0)

// ---------------- pack: int32 -> int8 ----------------
__global__ void pack_i32_to_i8(const int* __restrict__ in, char* __restrict__ out, int n16) {
    int i = blockIdx.x * blockDim.x + threadIdx.x;
    if (i >= n16) return;
    const i32x4* src = (const i32x4*)in + (size_t)i * 4;
    i32x4 r;
    r[0] = pack4(src[0]);
    r[1] = pack4(src[1]);
    r[2] = pack4(src[2]);
    r[3] = pack4(src[3]);
    ((i32x4*)out)[i] = r;
}

// ---- 128x256 tile, 4 waves (each 64x128), BK=64, 32x32x32 MFMA ----
// Serial-law optimized: wave reads 12 b128 per 16 MFMA (m_r=2,n_r=4).
// asm ds_read_b128 (r6-proven zero-conflict with the XOR slot swizzle).
__global__ __launch_bounds__(256, 2)
void gemm9(const char* __restrict__ A8, const char* __restrict__ B8,
           const int* __restrict__ bias,
           const int* __restrict__ qm_p, const int* __restrict__ ex_p,
           const int* __restrict__ zp_p, int* __restrict__ out) {
    // per buf: A 128x64 (8 KiB) @0, B 256x64 (16 KiB) @8192; 2 bufs -> 48 KiB
    __shared__ __align__(16) char smem[49152];
    lds_cchar* sbase = (lds_cchar*)smem;

    const int tid  = threadIdx.x;
    const int wid  = tid >> 6;
    const int lane = tid & 63;
    const int l31  = lane & 31;
    const int hc   = lane >> 5;            // 16B half of the 32-k slice
    const int wr   = wid >> 1;             // 0..1 : 64-row band
    const int wc   = wid & 1;              // 0..1 : 128-col band

    // XCD-bijective swizzle (512 % 8 == 0)
    const int bid = blockIdx.x;
    const int swz = (bid & 7) * 64 + (bid >> 3);
    const int bm  = swz >> 5;              // 0..15
    const int bn  = swz & 31;              // 0..31
    const int arow0 = bm * 128;
    const int brow0 = bn * 256;

    // staging: LDS row r, slot s = tid&3 holds logical chunk c = s ^ ((r>>1)&3)
    const int st_c = (tid & 3) ^ ((tid >> 3) & 3);
    const int r0   = tid >> 2;             // 0..63
    const char* agp = A8 + (size_t)(arow0 + r0) * Kdim + st_c * 16;
    const char* bgp = B8 + (size_t)(brow0 + r0) * Kdim + st_c * 16;

    auto stage = [&](int t) {
        const int buf = (t & 1) * 24576;
        const size_t ko = (size_t)t * BK;
        gload_lds16(agp + ko,                      &smem[buf + tid * 16]);
        gload_lds16(agp + ko + (size_t) 64 * Kdim, &smem[buf + tid * 16 + 4096]);
        gload_lds16(bgp + ko,                      &smem[buf + 8192 + tid * 16]);
        gload_lds16(bgp + ko + (size_t) 64 * Kdim, &smem[buf + 8192 + tid * 16 + 4096]);
        gload_lds16(bgp + ko + (size_t)128 * Kdim, &smem[buf + 8192 + tid * 16 + 8192]);
        gload_lds16(bgp + ko + (size_t)192 * Kdim, &smem[buf + 8192 + tid * 16 + 12288]);
    };

    // fragment offsets: slot = (2s+hc) ^ ((l31>>1)&3)  (row bands are 32-aligned)
    const int xr = (l31 >> 1) & 3;
    int aoff[2][2], boff[2][4];
#pragma unroll
    for (int s = 0; s < 2; ++s) {
        const int slot16 = ((2 * s + hc) ^ xr) * 16;
#pragma unroll
        for (int m = 0; m < 2; ++m)
            aoff[s][m] = (wr * 64 + m * 32 + l31) * 64 + slot16;
#pragma unroll
        for (int n = 0; n < 4; ++n)
            boff[s][n] = 8192 + (wc * 128 + n * 32 + l31) * 64 + slot16;
    }

    i32x16 acc[2][4] = {};

    stage(0);
    __syncthreads();
    for (int t = 0; t < NT; ++t) {
        const int buf = (t & 1) * 24576;
        i32x4 a[2][2], b[2][4];
#pragma unroll
        for (int s = 0; s < 2; ++s)
#pragma unroll
            for (int m = 0; m < 2; ++m)
                a[s][m] = dsread128(sbase + (buf + aoff[s][m]));
#pragma unroll
        for (int s = 0; s < 2; ++s)
#pragma unroll
            for (int n = 0; n < 4; ++n)
                b[s][n] = dsread128(sbase + (buf + boff[s][n]));
        if (t + 1 < NT) stage(t + 1);
        WAITLG0; SCHB;
        PRIO1;
#pragma unroll
        for (int m = 0; m < 2; ++m)
#pragma unroll
            for (int n = 0; n < 4; ++n)
#pragma unroll
                for (int s = 0; s < 2; ++s)
                    acc[m][n] = __builtin_amdgcn_mfma_i32_32x32x32_i8(
                        a[s][m], b[s][n], acc[m][n], 0, 0, 0);
        PRIO0;
        __syncthreads();
    }

    // ---------------- epilogue: requantize ----------------
    const int qm = *qm_p;
    const int ex = *ex_p;
    const int zp = *zp_p;
    const int rm = (qm < 2147418112) ? ((qm + (1 << 15)) >> 16) : 32767;
    const int shifts = 15 - ex;
    const long long rnd = (shifts > 0) ? (1LL << (shifts - 1)) : 0;

    int bv[4];
#pragma unroll
    for (int n = 0; n < 4; ++n) bv[n] = bias[brow0 + wc * 128 + n * 32 + l31];

#pragma unroll
    for (int m = 0; m < 2; ++m) {
        const int rbase = arow0 + wr * 64 + m * 32 + hc * 4;
#pragma unroll
        for (int n = 0; n < 4; ++n) {
            const int col = brow0 + wc * 128 + n * 32 + l31;
#pragma unroll
            for (int j = 0; j < 16; ++j) {
                const int row = rbase + (j & 3) + (j >> 2) * 8;
                long long t = (long long)(acc[m][n][j] + bv[n]) * rm + rnd;
                t >>= shifts;
                t += zp;
                t = t < -128 ? -128 : (t > 127 ? 127 : t);
                out[(size_t)row * Ndim + col] = (int)t;
            }
        }
    }
}

extern "C" void kernel_launch(void* const* d_in, const int* in_sizes, int n_in,
                              void* d_out, int out_size, void* d_ws, size_t ws_size,
                              hipStream_t stream) {
    const int* x32  = (const int*)d_in[0];
    const int* w32  = (const int*)d_in[1];
    const int* bias = (const int*)d_in[2];
    const int* qm   = (const int*)d_in[3];
    const int* ex   = (const int*)d_in[4];
    const int* zp   = (const int*)d_in[5];
    int* out = (int*)d_out;

    char* xa = (char*)d_ws;
    char* wa = xa + (size_t)Bdim * Kdim;
    const int nx16 = Bdim * Kdim / 16;   // 524288
    const int nw16 = Ndim * Kdim / 16;   // 2097152
    pack_i32_to_i8<<<(nx16 + 255) / 256, 256, 0, stream>>>(x32, xa, nx16);
    pack_i32_to_i8<<<(nw16 + 255) / 256, 256, 0, stream>>>(w32, wa, nw16);

    const int grid = (Bdim / 128) * (Ndim / 256);   // 16 * 32 = 512
    gemm9<<<grid, 256, 0, stream>>>(xa, wa, bias, qm, ex, zp, out);
}

// Round 10
// 105.497 us; speedup vs baseline: 1.2524x; 1.1299x over previous
//
#include <hip/hip_runtime.h>

#define DEVI __device__ __forceinline__

typedef int i32x4 __attribute__((ext_vector_type(4)));

static constexpr int Bdim = 2048;
static constexpr int Kdim = 4096;
static constexpr int Ndim = 8192;
static constexpr int BK   = 128;         // int8 k-elements per tile (128 B/row)
static constexpr int NT   = Kdim / BK;   // 32 K-tiles

typedef __attribute__((address_space(1))) const unsigned int gas_t;
typedef __attribute__((address_space(3))) unsigned int las_t;

DEVI void gload_lds16(const void* g, void* l) {
    __builtin_amdgcn_global_load_lds((gas_t*)g, (las_t*)l, 16, 0, 0);
}

DEVI int pack4(i32x4 v) {
    return (v[0] & 255) | ((v[1] & 255) << 8) | ((v[2] & 255) << 16) | (v[3] << 24);
}

// ---------------- pack: int32 -> int8 ----------------
__global__ void pack_i32_to_i8(const int* __restrict__ in, char* __restrict__ out, int n16) {
    int i = blockIdx.x * blockDim.x + threadIdx.x;
    if (i >= n16) return;
    const i32x4* src = (const i32x4*)in + (size_t)i * 4;
    i32x4 r;
    r[0] = pack4(src[0]);
    r[1] = pack4(src[1]);
    r[2] = pack4(src[2]);
    r[3] = pack4(src[3]);
    ((i32x4*)out)[i] = r;
}

// ---------------- 256x256 8-phase i8 GEMM, compiler-scheduled LDS reads ----------------
#define CFENCE asm volatile("" ::: "memory")
DEVI void bar() { CFENCE; __builtin_amdgcn_s_barrier(); CFENCE; }
#define WAITVM(N) asm volatile("s_waitcnt vmcnt(" #N ")" ::: "memory")
#define PRIO1 __builtin_amdgcn_s_setprio(1)
#define PRIO0 __builtin_amdgcn_s_setprio(0)

#define QUAD(MB)                                                                 \
    do {                                                                         \
        _Pragma("unroll") for (int mm = 0; mm < 4; ++mm)                         \
        _Pragma("unroll") for (int n = 0; n < 4; ++n)                            \
            acc[(MB) + mm][n] = __builtin_amdgcn_mfma_i32_16x16x64_i8(           \
                a[mm], b[n], acc[(MB) + mm][n], 0, 0, 0);                        \
    } while (0)

// One K-tile = 4 phases. Reads are PLAIN C++ loads (compiler emits ds_read_b128
// + fine-grained counted lgkmcnt before each MFMA -> intra-phase LDS||MFMA
// overlap, m97/m201 lineage). bar()'s memory clobber pins reads in-phase.
// Stage ring: P1->(t+1).A.ks1  P2->(t+2).B.ks0  P3->(t+2).A.ks0  P4->(t+2).B.ks1
#define TILE(CUR, S1, S2, S3, S4, VM)                                                 \
    {                                                                                 \
        { _Pragma("unroll") for (int mm = 0; mm < 4; ++mm) a[mm] = rdA(CUR, 0, mm);   \
          _Pragma("unroll") for (int n = 0; n < 4; ++n)    b[n]  = rdB(CUR, 0, n);    \
          S1; bar(); PRIO1; QUAD(0); PRIO0; bar(); }                                  \
        { _Pragma("unroll") for (int mm = 0; mm < 4; ++mm) a[mm] = rdA(CUR, 0, 4+mm); \
          S2; bar(); PRIO1; QUAD(4); PRIO0; bar(); }                                  \
        { _Pragma("unroll") for (int mm = 0; mm < 4; ++mm) a[mm] = rdA(CUR, 1, mm);   \
          _Pragma("unroll") for (int n = 0; n < 4; ++n)    b[n]  = rdB(CUR, 1, n);    \
          S3; bar(); PRIO1; QUAD(0); PRIO0; bar(); }                                  \
        { _Pragma("unroll") for (int mm = 0; mm < 4; ++mm) a[mm] = rdA(CUR, 1, 4+mm); \
          S4; bar(); PRIO1; QUAD(4); PRIO0; VM; bar(); }                              \
    }

__global__ __launch_bounds__(512, 2)
void gemm8(const char* __restrict__ A8, const char* __restrict__ B8,
           const int* __restrict__ bias,
           const int* __restrict__ qm_p, const int* __restrict__ ex_p,
           const int* __restrict__ zp_p, int* __restrict__ out) {
    // LDS (16B units): A [2 buf][2 ks][256 rows][4 slots] at 0, B same at 4096
    __shared__ i32x4 smem4[8192];                     // 128 KiB
    char* smem = (char*)smem4;

    const int tid  = threadIdx.x;
    const int wid  = tid >> 6;
    const int lane = tid & 63;
    const int l15  = lane & 15;
    const int lks  = lane >> 4;
    const int wr   = wid >> 2;   // 0..1
    const int wc   = wid & 3;    // 0..3

    // XCD swizzle: 256 blocks, each XCD gets one bm stripe
    const int bid = blockIdx.x;
    const int swz = (bid & 7) * 32 + (bid >> 3);
    const int bm  = swz >> 5;    // 0..7
    const int bn  = swz & 31;    // 0..31
    const int arow0 = bm * 256;
    const int brow0 = bn * 256;

    // T2 swizzle: phys slot = chunk ^ ((row>>1)&3); row bases 16-aligned =>
    // read selector = lks ^ ((l15>>1)&3). Offsets in 16B units.
    const int swsel = lks ^ ((l15 >> 1) & 3);
    const int a_rd16 = (wr * 128 + l15) * 4 + swsel;
    const int b_rd16 = 4096 + (wc * 64 + l15) * 4 + swsel;

    // stage addressing: thread covers (row = tid>>2 [+128], chunk = st_c)
    const int st_c = (tid & 3) ^ ((tid >> 3) & 3);
    const char* agp = A8 + (size_t)(arow0 + (tid >> 2)) * Kdim + st_c * 16;
    const char* bgp = B8 + (size_t)(brow0 + (tid >> 2)) * Kdim + st_c * 16;

    auto stage = [&](int isb, int t, int ks) {
        const char* gp = (isb ? bgp : agp) + (size_t)t * BK + ks * 64;
        const int lb = (isb ? 65536 : 0) + (t & 1) * 32768 + ks * 16384 + tid * 16;
        gload_lds16(gp, &smem[lb]);
        gload_lds16(gp + (size_t)128 * Kdim, &smem[lb + 8192]);
    };
    auto rdA = [&](int buf, int ks, int m) {
        return smem4[buf * 2048 + ks * 1024 + a_rd16 + m * 64];
    };
    auto rdB = [&](int buf, int ks, int n) {
        return smem4[buf * 2048 + ks * 1024 + b_rd16 + n * 64];
    };

    i32x4 acc[8][4] = {};
    i32x4 a[4], b[4];

    // prologue: 7 units in steady-state order; vmcnt(6) => tile 0 landed
    stage(1, 0, 0); stage(0, 0, 0); stage(1, 0, 1); stage(0, 0, 1);
    stage(1, 1, 0); stage(0, 1, 0); stage(1, 1, 1);
    WAITVM(6);
    bar();

    int cur = 0;
    for (int t = 0; t < NT - 2; ++t) {   // t = 0..29, all stages valid
        TILE(cur,
             stage(0, t + 1, 1),
             stage(1, t + 2, 0),
             stage(0, t + 2, 0),
             stage(1, t + 2, 1),
             WAITVM(6));
        cur ^= 1;
    }
    // t = NT-2: only (NT-1).A.ks1 left to stage; drain fully
    TILE(cur,
         stage(0, NT - 1, 1),
         ((void)0), ((void)0), ((void)0),
         WAITVM(0));
    cur ^= 1;
    // t = NT-1: pure compute
    TILE(cur, ((void)0), ((void)0), ((void)0), ((void)0), ((void)0));

    // ---------------- epilogue: requantize ----------------
    const int qm = *qm_p;
    const int ex = *ex_p;
    const int zp = *zp_p;
    const int rm = (qm < 2147418112) ? ((qm + (1 << 15)) >> 16) : 32767;
    const int shifts = 15 - ex;
    const long long rnd = (shifts > 0) ? (1LL << (shifts - 1)) : 0;

    int bv[4];
#pragma unroll
    for (int n = 0; n < 4; ++n) bv[n] = bias[brow0 + wc * 64 + n * 16 + l15];

#pragma unroll
    for (int m = 0; m < 8; ++m) {
        const int row0 = arow0 + wr * 128 + m * 16 + lks * 4;
#pragma unroll
        for (int n = 0; n < 4; ++n) {
            const int col = brow0 + wc * 64 + n * 16 + l15;
#pragma unroll
            for (int j = 0; j < 4; ++j) {
                long long t = (long long)(acc[m][n][j] + bv[n]) * rm + rnd;
                t >>= shifts;
                t += zp;
                t = t < -128 ? -128 : (t > 127 ? 127 : t);
                out[(size_t)(row0 + j) * Ndim + col] = (int)t;
            }
        }
    }
}

extern "C" void kernel_launch(void* const* d_in, const int* in_sizes, int n_in,
                              void* d_out, int out_size, void* d_ws, size_t ws_size,
                              hipStream_t stream) {
    const int* x32  = (const int*)d_in[0];
    const int* w32  = (const int*)d_in[1];
    const int* bias = (const int*)d_in[2];
    const int* qm   = (const int*)d_in[3];
    const int* ex   = (const int*)d_in[4];
    const int* zp   = (const int*)d_in[5];
    int* out = (int*)d_out;

    char* xa = (char*)d_ws;
    char* wa = xa + (size_t)Bdim * Kdim;
    const int nx16 = Bdim * Kdim / 16;   // 524288
    const int nw16 = Ndim * Kdim / 16;   // 2097152
    pack_i32_to_i8<<<(nx16 + 255) / 256, 256, 0, stream>>>(x32, xa, nx16);
    pack_i32_to_i8<<<(nw16 + 255) / 256, 256, 0, stream>>>(w32, wa, nw16);

    const int grid = (Bdim / 256) * (Ndim / 256);   // 8 * 32 = 256
    gemm8<<<grid, 512, 0, stream>>>(xa, wa, bias, qm, ex, zp, out);
}